// Round 6
// baseline (399.904 us; speedup 1.0000x reference)
//
#include <hip/hip_runtime.h>
#include <stdint.h>

// GraphAttention: B=2, N=4096, C=256, H=4, D=64. Inputs fp32, adj int32,
// OUTPUT FP32 (proven r6/r7). Threshold = 2% of ref absmax = 0.0609.
// Fixed harness overhead ~175us?? (r12 estimate; being re-measured this round).
// r14: attn rebuilt as 32x32x16 swapped-QK^T (m214 ladder). 353.6 -> 317.7.
// r15: z=4 occupancy push + setprio. 317.7 -> 309.9.
// r16/r17: intra-wave 2-tile pipeline: NO GAIN (307.9).
// r18: 64 q/wave, LDS reads halved: NO GAIN (307.6). Three orthogonal attn
//      fixes = 0 -> the "attn ~60us" premise itself is suspect.
// r19: MEASUREMENT PROBE. attn_mfma is idempotent (pure writes); launch it
//      3x. dur_us delta = 2*(attn + launch). Kernel code byte-identical to
//      r18. ~430us => attn~60 (model A, keep attacking attn); ~370us =>
//      attn~30 (model B, near floor; pivot to overhead/fusion next round).
#define CDIM 256
#define HEADS 4
#define HD 64
#define NB 2
#define NN 4096

typedef unsigned short u16;
typedef unsigned char u8;
typedef unsigned long long u64;
typedef __attribute__((ext_vector_type(8))) short short8;   // bf16x8 frag
typedef __attribute__((ext_vector_type(4))) float f32x4;    // 16x16 C/D frag
typedef __attribute__((ext_vector_type(16))) float f32x16;  // 32x32 C/D frag

// 0.125 (1/sqrt(64)) * log2(e): folded into Q so softmax uses exp2
#define QSCALE 0.1803368801111244f

__device__ __forceinline__ u16 f2bf(float f) {  // RNE
  union { float f; unsigned u; } v; v.f = f;
  return (u16)((v.u + 0x7fffu + ((v.u >> 16) & 1u)) >> 16);
}
__device__ __forceinline__ float bf2f(u16 u) {
  union { unsigned u; float f; } v; v.u = ((unsigned)u) << 16; return v.f;
}
// load MFMA frag from fp32 global, converting to bf16 in-reg
__device__ __forceinline__ short8 fragf32(const float* p) {
  float4 a = reinterpret_cast<const float4*>(p)[0];
  float4 b = reinterpret_cast<const float4*>(p)[1];
  short8 h;
  h[0] = (short)f2bf(a.x); h[1] = (short)f2bf(a.y);
  h[2] = (short)f2bf(a.z); h[3] = (short)f2bf(a.w);
  h[4] = (short)f2bf(b.x); h[5] = (short)f2bf(b.y);
  h[6] = (short)f2bf(b.z); h[7] = (short)f2bf(b.w);
  return h;
}
__device__ __forceinline__ f32x16 zero16() {
  f32x16 z;
#pragma unroll
  for (int i = 0; i < 16; ++i) z[i] = 0.f;
  return z;
}
__device__ __forceinline__ unsigned cvt_pk_bf16(float lo, float hi) {
  unsigned r;
  asm("v_cvt_pk_bf16_f32 %0, %1, %2" : "=v"(r) : "v"(lo), "v"(hi));
  return r;
}
// a' = [a_lo | b_lo], b' = [a_hi | b_hi]
__device__ __forceinline__ void permlane32_swap(unsigned& a, unsigned& b) {
  asm("v_permlane32_swap_b32 %0, %1" : "+v"(a), "+v"(b));
}
// masked exp2 + li tree-sum + pack to PV A-frags for one 32-reg S half
__device__ __forceinline__ void smax_half(const f32x16& s, unsigned m32,
                                          uint4& pfa, uint4& pfb, float& li) {
  float pp[16];
#pragma unroll
  for (int r = 0; r < 16; ++r) {
    const int c = (r & 3) + 8 * (r >> 2);
    pp[r] = ((m32 >> c) & 1u) ? __builtin_amdgcn_exp2f(s[r]) : 0.f;
  }
  float t0 = (pp[0] + pp[1]) + (pp[2] + pp[3]);
  float t1 = (pp[4] + pp[5]) + (pp[6] + pp[7]);
  float t2 = (pp[8] + pp[9]) + (pp[10] + pp[11]);
  float t3 = (pp[12] + pp[13]) + (pp[14] + pp[15]);
  li += (t0 + t1) + (t2 + t3);
  unsigned wAe = cvt_pk_bf16(pp[0], pp[1]),  wBe = cvt_pk_bf16(pp[2], pp[3]);
  unsigned wAo = cvt_pk_bf16(pp[4], pp[5]),  wBo = cvt_pk_bf16(pp[6], pp[7]);
  permlane32_swap(wAe, wAo);
  permlane32_swap(wBe, wBo);
  pfa = (uint4){wAe, wBe, wAo, wBo};
  wAe = cvt_pk_bf16(pp[8], pp[9]);   wBe = cvt_pk_bf16(pp[10], pp[11]);
  wAo = cvt_pk_bf16(pp[12], pp[13]); wBo = cvt_pk_bf16(pp[14], pp[15]);
  permlane32_swap(wAe, wAo);
  permlane32_swap(wBe, wBo);
  pfb = (uint4){wAe, wBe, wAo, wBo};
}

// ---------------------------------------------------------------------------
// Launch 1: prep. Blocks 0..4095: adj -> bitmask, streaming. Blocks
// 4096..4223: W fp32->bf16 (4 matrices, 2048 elems/block).
// ---------------------------------------------------------------------------
__global__ __launch_bounds__(256) void prep(
    const int* __restrict__ adj, u8* __restrict__ bmb,
    const float* __restrict__ Wq, const float* __restrict__ Wk,
    const float* __restrict__ Wv, const float* __restrict__ Wo,
    u16* __restrict__ Wqb, u16* __restrict__ Wkb,
    u16* __restrict__ Wvb, u16* __restrict__ Wob) {
  const int blk = blockIdx.x;
  if (blk < 4096) {
    const int wave = threadIdx.x >> 6, lane = threadIdx.x & 63;
    const int c0 = blk * 16 + wave * 4;  // 4 chunks of 512 keys per wave
#pragma unroll
    for (int it = 0; it < 4; ++it) {
      int c = c0 + it;
      int row = c >> 3, kb = (c & 7) * 512;
      const int* src = adj + (size_t)row * 4096 + kb + lane * 8;
      uint4 a = *reinterpret_cast<const uint4*>(src);
      uint4 b = *reinterpret_cast<const uint4*>(src + 4);
      unsigned byte = 0;
      byte |= (a.x != 0) ? 1u : 0u;
      byte |= (a.y != 0) ? 2u : 0u;
      byte |= (a.z != 0) ? 4u : 0u;
      byte |= (a.w != 0) ? 8u : 0u;
      byte |= (b.x != 0) ? 16u : 0u;
      byte |= (b.y != 0) ? 32u : 0u;
      byte |= (b.z != 0) ? 64u : 0u;
      byte |= (b.w != 0) ? 128u : 0u;
      bmb[(size_t)row * 512 + (c & 7) * 64 + lane] = (u8)byte;
    }
  } else {
    size_t base = ((size_t)(blk - 4096) * 256 + threadIdx.x) * 8;  // <262144
    int w = (int)(base >> 16);
    size_t lo = base & 65535;
    const float* src;
    u16* dst;
    if (w == 0)      { src = Wq + lo; dst = Wqb + lo; }
    else if (w == 1) { src = Wk + lo; dst = Wkb + lo; }
    else if (w == 2) { src = Wv + lo; dst = Wvb + lo; }
    else             { src = Wo + lo; dst = Wob + lo; }
    *reinterpret_cast<short8*>(dst) = fragf32(src);
  }
}

// ---------------------------------------------------------------------------
// Launch 2: fused QKV projection (MFMA). Grid (512, 3). y=0: Qb (scaled);
// y=1: Kb; y=2: Vtb[bh][d][n] (transposed output).
// ---------------------------------------------------------------------------
__global__ __launch_bounds__(256) void qkv_gemm(
    const float* __restrict__ x,
    const u16* __restrict__ Wqb, const u16* __restrict__ Wkb,
    const u16* __restrict__ Wvb,
    const float* __restrict__ bq, const float* __restrict__ bk,
    const float* __restrict__ bv,
    u16* __restrict__ Qb, u16* __restrict__ Kb, u16* __restrict__ Vtb) {
  const int tid = threadIdx.x, w = tid >> 6, lane = tid & 63;
  const int quad = lane >> 4, l15 = lane & 15;
  const int tok0 = blockIdx.x * 16;
  const int b = tok0 >> 12, nl = tok0 & 4095;
  const int ym = blockIdx.y;

  f32x4 acc[4];
#pragma unroll
  for (int i = 0; i < 4; ++i) acc[i] = (f32x4){0.f, 0.f, 0.f, 0.f};

  if (ym < 2) {
    const u16* Wb = (ym == 0) ? Wqb : Wkb;
    const float* bias = (ym == 0) ? bq : bk;
    const float scale = (ym == 0) ? QSCALE : 1.0f;
    u16* outp = (ym == 0) ? Qb : Kb;
#pragma unroll
    for (int ks = 0; ks < 8; ++ks) {
      short8 af = fragf32(x + (size_t)(tok0 + l15) * 256 + ks * 32 + quad * 8);
#pragma unroll
      for (int ns = 0; ns < 4; ++ns) {
        short8 bf = *reinterpret_cast<const short8*>(
            &Wb[(size_t)(w * 64 + ns * 16 + l15) * 256 + ks * 32 + quad * 8]);
        acc[ns] = __builtin_amdgcn_mfma_f32_16x16x32_bf16(af, bf, acc[ns], 0, 0, 0);
      }
    }
#pragma unroll
    for (int ns = 0; ns < 4; ++ns) {
      int d = ns * 16 + l15;
      float bb = bias[w * 64 + d];
#pragma unroll
      for (int r = 0; r < 4; ++r) {
        int tok = nl + quad * 4 + r;
        outp[((size_t)(b * HEADS + w) * NN + tok) * HD + d] =
            f2bf((acc[ns][r] + bb) * scale);
      }
    }
  } else {
#pragma unroll
    for (int ks = 0; ks < 8; ++ks) {
      short8 xf = fragf32(x + (size_t)(tok0 + l15) * 256 + ks * 32 + quad * 8);
#pragma unroll
      for (int ms = 0; ms < 4; ++ms) {
        short8 wf = *reinterpret_cast<const short8*>(
            &Wvb[(size_t)(w * 64 + ms * 16 + l15) * 256 + ks * 32 + quad * 8]);
        acc[ms] = __builtin_amdgcn_mfma_f32_16x16x32_bf16(wf, xf, acc[ms], 0, 0, 0);
      }
    }
#pragma unroll
    for (int ms = 0; ms < 4; ++ms) {
#pragma unroll
      for (int r = 0; r < 4; ++r) {
        int d = ms * 16 + quad * 4 + r;
        float bb = bv[w * 64 + d];
        Vtb[((size_t)((b * HEADS + w) * HD + d)) * NN + nl + l15] =
            f2bf(acc[ms][r] + bb);
      }
    }
  }
}

// ---------------------------------------------------------------------------
// Launch 3: attention, 32x32x16 swapped-QK^T, 64 q-rows/wave (2 subtiles).
// Block = 4 waves x 64 q = 256 q; one bh; one key-QUARTER (1024 keys, NT=16).
// Grid (16, 8, 4) = 512 blocks = 2/CU. Every K/V fragment ds_read feeds 4
// MFMAs (subtiles A,B). li via VALU tree-sum. K/V double-buffered LDS,
// XOR-swizzled rows, 1 barrier/tile. (r18 structure, unchanged.)
// ---------------------------------------------------------------------------
#define QKT_DK2(QFA, QFB, SD)                                                  \
  { short8 ka_ = *reinterpret_cast<const short8*>(&KVs[cbq + l31 * 64 + SD]);  \
    short8 kc_ =                                                               \
        *reinterpret_cast<const short8*>(&KVs[cbq + 2048 + l31 * 64 + SD]);    \
    sA0 = __builtin_amdgcn_mfma_f32_32x32x16_bf16(ka_, QFA, sA0, 0, 0, 0);     \
    sB0 = __builtin_amdgcn_mfma_f32_32x32x16_bf16(ka_, QFB, sB0, 0, 0, 0);     \
    sA1 = __builtin_amdgcn_mfma_f32_32x32x16_bf16(kc_, QFA, sA1, 0, 0, 0);     \
    sB1 = __builtin_amdgcn_mfma_f32_32x32x16_bf16(kc_, QFB, sB1, 0, 0, 0); }

#define PV_KB2(PFA, PFB, SD)                                                   \
  { union { uint4 u; short8 s; } ua_, ub_;                                     \
    ua_.u = PFA; ub_.u = PFB;                                                  \
    short8 vf0_ =                                                              \
        *reinterpret_cast<const short8*>(&KVs[cbq + 4096 + l31 * 64 + SD]);    \
    short8 vf1_ =                                                              \
        *reinterpret_cast<const short8*>(&KVs[cbq + 6144 + l31 * 64 + SD]);    \
    OaccA0 = __builtin_amdgcn_mfma_f32_32x32x16_bf16(ua_.s, vf0_, OaccA0, 0, 0, 0); \
    OaccA1 = __builtin_amdgcn_mfma_f32_32x32x16_bf16(ua_.s, vf1_, OaccA1, 0, 0, 0); \
    OaccB0 = __builtin_amdgcn_mfma_f32_32x32x16_bf16(ub_.s, vf0_, OaccB0, 0, 0, 0); \
    OaccB1 = __builtin_amdgcn_mfma_f32_32x32x16_bf16(ub_.s, vf1_, OaccB1, 0, 0, 0); }

__global__ __launch_bounds__(256, 2) void attn_mfma(
    const u16* __restrict__ Qb, const u16* __restrict__ Kb,
    const u16* __restrict__ Vtb, const u64* __restrict__ bm,
    u16* __restrict__ Opb, float* __restrict__ Lp) {
  // 2 buffers x (K tile [64][64] + V tile [64][64]) bf16, XOR-swizzled rows
  __shared__ __align__(16) u16 KVs[2 * 8192];  // 32 KB

  const int tid = threadIdx.x;
  const int wave = tid >> 6, lane = tid & 63;
  const int h5 = lane >> 5, l31 = lane & 31, l7 = lane & 7;
  const int bh = blockIdx.y, b = bh >> 2, h = bh & 3;
  const int q0 = blockIdx.x * 256 + wave * 64;
  const int quarter = blockIdx.z;
  const int key0 = quarter * 1024;
  const int NT = 16;  // 1024 keys / 64

  // Q B-frags, subtile A rows q0..q0+31, subtile B rows q0+32..q0+63
  const u16* qrA = Qb + ((size_t)bh * NN + q0 + l31) * HD + h5 * 8;
  const short8 qfA0 = *reinterpret_cast<const short8*>(qrA);
  const short8 qfA1 = *reinterpret_cast<const short8*>(qrA + 16);
  const short8 qfA2 = *reinterpret_cast<const short8*>(qrA + 32);
  const short8 qfA3 = *reinterpret_cast<const short8*>(qrA + 48);
  const u16* qrB = qrA + 32 * HD;
  const short8 qfB0 = *reinterpret_cast<const short8*>(qrB);
  const short8 qfB1 = *reinterpret_cast<const short8*>(qrB + 16);
  const short8 qfB2 = *reinterpret_cast<const short8*>(qrB + 32);
  const short8 qfB3 = *reinterpret_cast<const short8*>(qrB + 48);

  f32x16 OaccA0 = zero16(), OaccA1 = zero16();
  f32x16 OaccB0 = zero16(), OaccB1 = zero16();
  float liA = 0.f, liB = 0.f;

  // frag-read slot offsets (u16 units): slot j -> ((2j+h5)^l7)*8
  int sdk[4];
#pragma unroll
  for (int j = 0; j < 4; ++j) sdk[j] = ((2 * j + h5) ^ l7) << 3;

  // staging: thread -> row tid>>2 (0..63), slots (tid&3)*2, +1 (swizzled)
  const int srow = tid >> 2;
  const int wbu0 = ((((tid & 3) * 2)     ^ (srow & 7)) << 3) + srow * 64;
  const int wbu1 = ((((tid & 3) * 2 + 1) ^ (srow & 7)) << 3) + srow * 64;

  const u16* kbase = Kb + (size_t)bh * NN * HD + (size_t)key0 * HD;
  const u16* vbase = Vtb + (size_t)bh * HD * NN + key0;
  const u64* bmrA = bm + ((size_t)b * NN + q0 + l31) * 64 + quarter * 16;
  const u64* bmrB = bmrA + (size_t)32 * 64;

  uint4 k0, k1, v0, v1;
  {  // tile 0 load
    const uint4* kp = reinterpret_cast<const uint4*>(kbase) + tid * 2;
    k0 = kp[0]; k1 = kp[1];
    const u16* vp = vbase + (size_t)srow * NN + (tid & 3) * 16;
    v0 = *reinterpret_cast<const uint4*>(vp);
    v1 = *reinterpret_cast<const uint4*>(vp + 8);
  }
  // stage tile 0 into buffer 0
  *reinterpret_cast<uint4*>(&KVs[wbu0]) = k0;
  *reinterpret_cast<uint4*>(&KVs[wbu1]) = k1;
  *reinterpret_cast<uint4*>(&KVs[4096 + wbu0]) = v0;
  *reinterpret_cast<uint4*>(&KVs[4096 + wbu1]) = v1;
  {  // prefetch tile 1
    const uint4* kp = reinterpret_cast<const uint4*>(kbase + 4096) + tid * 2;
    k0 = kp[0]; k1 = kp[1];
    const u16* vp = vbase + (size_t)srow * NN + 64 + (tid & 3) * 16;
    v0 = *reinterpret_cast<const uint4*>(vp);
    v1 = *reinterpret_cast<const uint4*>(vp + 8);
  }
  u64 amA_c = bmrA[0], amB_c = bmrB[0];

  for (int mt = 0; mt < NT; ++mt) {
    __syncthreads();  // buf[mt&1] staged by all waves; prev-tile reads done
    const u64 amA = amA_c, amB = amB_c;
    if (mt + 1 < NT) { amA_c = bmrA[mt + 1]; amB_c = bmrB[mt + 1]; }
    const int cbq = (mt & 1) * 8192;  // current buffer base (u16)

    // ---- QK^T swapped, both subtiles share every K fragment ----
    f32x16 sA0 = zero16(), sA1 = zero16();
    f32x16 sB0 = zero16(), sB1 = zero16();
    __builtin_amdgcn_s_setprio(1);
    QKT_DK2(qfA0, qfB0, sdk[0]);
    QKT_DK2(qfA1, qfB1, sdk[1]);
    QKT_DK2(qfA2, qfB2, sdk[2]);
    QKT_DK2(qfA3, qfB3, sdk[3]);
    __builtin_amdgcn_s_setprio(0);

    // lane's q-rows: A = q0+l31, B = q0+32+l31. Pre-shift masks by 4*h5.
    const u64 ashA = amA >> (4 * h5);
    const u64 ashB = amB >> (4 * h5);

    uint4 pA0, pA1, pA2, pA3, pB0, pB1, pB2, pB3;
    smax_half(sA0, (unsigned)ashA, pA0, pA1, liA);
    smax_half(sA1, (unsigned)(ashA >> 32), pA2, pA3, liA);
    smax_half(sB0, (unsigned)ashB, pB0, pB1, liB);
    smax_half(sB1, (unsigned)(ashB >> 32), pB2, pB3, liB);

    // ---- PV, both subtiles share every V fragment ----
    __builtin_amdgcn_s_setprio(1);
    PV_KB2(pA0, pB0, sdk[0]);
    PV_KB2(pA1, pB1, sdk[1]);
    PV_KB2(pA2, pB2, sdk[2]);
    PV_KB2(pA3, pB3, sdk[3]);
    __builtin_amdgcn_s_setprio(0);

    // ---- stage next tile into alt buffer; prefetch tile mt+2 ----
    if (mt + 1 < NT) {
      const int nb = ((mt + 1) & 1) * 8192;
      *reinterpret_cast<uint4*>(&KVs[nb + wbu0]) = k0;
      *reinterpret_cast<uint4*>(&KVs[nb + wbu1]) = k1;
      *reinterpret_cast<uint4*>(&KVs[nb + 4096 + wbu0]) = v0;
      *reinterpret_cast<uint4*>(&KVs[nb + 4096 + wbu1]) = v1;
      if (mt + 2 < NT) {
        const uint4* kp =
            reinterpret_cast<const uint4*>(kbase + (size_t)(mt + 2) * 4096) + tid * 2;
        k0 = kp[0]; k1 = kp[1];
        const u16* vp = vbase + (size_t)srow * NN + (mt + 2) * 64 + (tid & 3) * 16;
        v0 = *reinterpret_cast<const uint4*>(vp);
        v1 = *reinterpret_cast<const uint4*>(vp + 8);
      }
    }
  }

  // epilogue: Oacc reg r -> O[q + (r&3)+8*(r>>2)+4*h5][d-half + l31]
  u16* ob = Opb + (size_t)(quarter * NB + b) * NN * CDIM;
#pragma unroll
  for (int r = 0; r < 16; ++r) {
    const int tokA = q0 + (r & 3) + 8 * (r >> 2) + 4 * h5;
    u16* orA = ob + (size_t)tokA * CDIM + h * HD;
    orA[l31] = f2bf(OaccA0[r]);
    orA[32 + l31] = f2bf(OaccA1[r]);
    u16* orB = orA + (size_t)32 * CDIM;
    orB[l31] = f2bf(OaccB0[r]);
    orB[32 + l31] = f2bf(OaccB1[r]);
  }
  {  // li: combine h5 halves (lane and lane^32 hold complementary keys)
    unsigned a0 = __float_as_uint(liA), a1 = a0;
    permlane32_swap(a0, a1);
    float liAf = __uint_as_float(a0) + __uint_as_float(a1);
    unsigned b0 = __float_as_uint(liB), b1 = b0;
    permlane32_swap(b0, b1);
    float liBf = __uint_as_float(b0) + __uint_as_float(b1);
    if (lane < 32) {
      float* lrow = Lp + ((size_t)quarter * 8 + bh) * NN;
      lrow[q0 + lane] = liAf;
      lrow[q0 + 32 + lane] = liBf;
    }
  }
}

// ---------------------------------------------------------------------------
// Launch 4: combine quarters + output projection (MFMA) + LayerNorm.
// ---------------------------------------------------------------------------
__global__ __launch_bounds__(256) void comb_oproj(
    const u16* __restrict__ Opb, const float* __restrict__ Lp,
    const u16* __restrict__ Wob, const float* __restrict__ bo,
    const float* __restrict__ gamma, const float* __restrict__ beta,
    float* __restrict__ out) {
  __shared__ u16 As[16 * 264];
  __shared__ float ys[16][264];
  __shared__ float linv[64];
  const int tid = threadIdx.x, w = tid >> 6, lane = tid & 63;
  const int quad = lane >> 4, l15 = lane & 15;
  const int tok0 = blockIdx.x * 16;
  const int b = tok0 >> 12, nl = tok0 & 4095;

  if (tid < 64) {
    int tokr = tid >> 2, hh = tid & 3;
    int bh = b * 4 + hh;
    int n = nl + tokr;
    float s = 0.f;
#pragma unroll
    for (int q = 0; q < 4; ++q)
      s += Lp[((size_t)q * 8 + bh) * NN + n];
    linv[tokr * 4 + hh] = (s > 0.f) ? (1.f / s) : 0.f;
  }
  __syncthreads();

  {
    int tokr = tid >> 4, ch0 = (tid & 15) * 16;
    size_t base = ((size_t)b * NN + nl + tokr) * CDIM + ch0;
    float inv = linv[tokr * 4 + (ch0 >> 6)];
    float acc16[16];
#pragma unroll
    for (int i = 0; i < 16; ++i) acc16[i] = 0.f;
#pragma unroll
    for (int q = 0; q < 4; ++q) {
      size_t qb = (size_t)q * 2097152 + base;
      uint4 a0 = *reinterpret_cast<const uint4*>(Opb + qb);
      uint4 a1 = *reinterpret_cast<const uint4*>(Opb + qb + 8);
      unsigned wa[8] = {a0.x, a0.y, a0.z, a0.w, a1.x, a1.y, a1.z, a1.w};
#pragma unroll
      for (int i = 0; i < 8; ++i) {
        acc16[2 * i]     += bf2f((u16)(wa[i] & 0xffffu));
        acc16[2 * i + 1] += bf2f((u16)(wa[i] >> 16));
      }
    }
    u16 ov[16];
#pragma unroll
    for (int i = 0; i < 16; ++i) ov[i] = f2bf(acc16[i] * inv);
    u16* dst = &As[tokr * 264 + ch0];
    *reinterpret_cast<uint4*>(dst) = *reinterpret_cast<uint4*>(ov);
    *reinterpret_cast<uint4*>(dst + 8) = *reinterpret_cast<uint4*>(ov + 8);
  }
  __syncthreads();

  f32x4 acc[4];
#pragma unroll
  for (int i = 0; i < 4; ++i) acc[i] = (f32x4){0.f, 0.f, 0.f, 0.f};
#pragma unroll
  for (int ks = 0; ks < 8; ++ks) {
    short8 af = *reinterpret_cast<const short8*>(&As[l15 * 264 + ks * 32 + quad * 8]);
#pragma unroll
    for (int ns = 0; ns < 4; ++ns) {
      short8 bf = *reinterpret_cast<const short8*>(
          &Wob[(size_t)(w * 64 + ns * 16 + l15) * 256 + ks * 32 + quad * 8]);
      acc[ns] = __builtin_amdgcn_mfma_f32_16x16x32_bf16(af, bf, acc[ns], 0, 0, 0);
    }
  }

#pragma unroll
  for (int ns = 0; ns < 4; ++ns) {
    int ch = w * 64 + ns * 16 + l15;
    float bb = bo[ch];
#pragma unroll
    for (int r = 0; r < 4; ++r) ys[quad * 4 + r][ch] = acc[ns][r] + bb;
  }
  __syncthreads();

  float g[4], bt[4];
#pragma unroll
  for (int i = 0; i < 4; ++i) {
    g[i] = gamma[lane + i * 64];
    bt[i] = beta[lane + i * 64];
  }
#pragma unroll
  for (int rr = 0; rr < 4; ++rr) {
    int r = w * 4 + rr;
    float v[4], s = 0.f, s2 = 0.f;
#pragma unroll
    for (int i = 0; i < 4; ++i) {
      v[i] = ys[r][lane + i * 64];
      s += v[i];
      s2 = fmaf(v[i], v[i], s2);
    }
#pragma unroll
    for (int off = 32; off > 0; off >>= 1) {
      s += __shfl_xor(s, off, 64);
      s2 += __shfl_xor(s2, off, 64);
    }
    float mu = s * (1.f / 256.f);
    float rs = rsqrtf(s2 * (1.f / 256.f) - mu * mu + 1e-5f);
    float* orow = out + (size_t)(tok0 + r) * 256;
#pragma unroll
    for (int i = 0; i < 4; ++i)
      orow[lane + i * 64] = (v[i] - mu) * rs * g[i] + bt[i];
  }
}

// ---------------------------------------------------------------------------
extern "C" void kernel_launch(void* const* d_in, const int* in_sizes, int n_in,
                              void* d_out, int out_size, void* d_ws, size_t ws_size,
                              hipStream_t stream) {
  const float* x     = (const float*)d_in[0];
  const int*   adj   = (const int*)d_in[1];
  const float* Wq    = (const float*)d_in[2];
  const float* bq    = (const float*)d_in[3];
  const float* Wk    = (const float*)d_in[4];
  const float* bk    = (const float*)d_in[5];
  const float* Wv    = (const float*)d_in[6];
  const float* bv    = (const float*)d_in[7];
  const float* Wo    = (const float*)d_in[8];
  const float* bo    = (const float*)d_in[9];
  const float* gamma = (const float*)d_in[10];
  const float* beta  = (const float*)d_in[11];
  float* out = (float*)d_out;

  const size_t PER = (size_t)NB * HEADS * NN * HD;  // 2,097,152
  u16* Wqb = (u16*)d_ws;                 // 65,536 each
  u16* Wkb = Wqb + 65536;
  u16* Wvb = Wkb + 65536;
  u16* Wob = Wvb + 65536;
  u64* bmp = (u64*)(Wob + 65536);        // 524,288 u64 (4 MB), 8B-aligned
  u16* Qb  = (u16*)(bmp + 524288);
  u16* Kb  = Qb + PER;
  u16* Vtb = Kb + PER;
  u16* Opb = Vtb + PER;                  // 4 x PER bf16 (quarter partials)
  float* Lp = (float*)(Opb + 4 * PER);   // 131,072 fp32

  const size_t NEED = (size_t)((u16*)(Lp + 131072) - (u16*)d_ws) * sizeof(u16);
  if (ws_size < NEED) return;

  prep<<<dim3(4224), dim3(256), 0, stream>>>(
      adj, (u8*)bmp, Wq, Wk, Wv, Wo, Wqb, Wkb, Wvb, Wob);

  qkv_gemm<<<dim3(512, 3), dim3(256), 0, stream>>>(
      x, Wqb, Wkb, Wvb, bq, bk, bv, Qb, Kb, Vtb);

  // r19 PROBE: attn launched 3x (idempotent). dur_us delta vs r18 =
  // 2*(attn_dur + launch_overhead). Revert to 1x next round.
  attn_mfma<<<dim3(NN / 256, NB * HEADS, 4), dim3(256), 0, stream>>>(
      Qb, Kb, Vtb, bmp, Opb, Lp);
  attn_mfma<<<dim3(NN / 256, NB * HEADS, 4), dim3(256), 0, stream>>>(
      Qb, Kb, Vtb, bmp, Opb, Lp);
  attn_mfma<<<dim3(NN / 256, NB * HEADS, 4), dim3(256), 0, stream>>>(
      Qb, Kb, Vtb, bmp, Opb, Lp);

  comb_oproj<<<dim3((NB * NN) / 16), dim3(256), 0, stream>>>(
      Opb, Lp, Wob, bo, gamma, beta, out);
}

// Round 7
// 374.343 us; speedup vs baseline: 1.0683x; 1.0683x over previous
//
#include <hip/hip_runtime.h>
#include <stdint.h>

// GraphAttention: B=2, N=4096, C=256, H=4, D=64. Inputs fp32, adj int32,
// OUTPUT FP32 (proven r6/r7). Threshold = 2% of ref absmax = 0.0609.
// r14: attn 32x32x16 swapped-QK^T. 353.6 -> 317.7.
// r15: z=4 + setprio. -> 309.9.   r16/r17: 2-tile pipeline: ~0 (307.9).
// r18: 64 q/wave, LDS reads halved: ~0 (307.6).
// r19: 3x-launch probe => attn = 46.2us/launch. Pipe model (per-SIMD units,
//      rule-15 fix): MFMA 13.7 + softmaxVALU ~18 + LDS ~10 ~= serial 42+bar
//      ~= 46 measured => phases nearly SERIAL.
// r20: ABLATION PROBE: launches = [noSM, noSM, full]. noSM drops bit-test+
//      exp2+li (keeps QK^T, mask gathers via xor-keep, cvt_pk pack, PV,
//      staging). Final full launch overwrites all outputs -> correct.
//      (dur-307.6)/2 vs 46.2 isolates softmax-VALU's critical-path share.
#define CDIM 256
#define HEADS 4
#define HD 64
#define NB 2
#define NN 4096

typedef unsigned short u16;
typedef unsigned char u8;
typedef unsigned long long u64;
typedef __attribute__((ext_vector_type(8))) short short8;   // bf16x8 frag
typedef __attribute__((ext_vector_type(4))) float f32x4;    // 16x16 C/D frag
typedef __attribute__((ext_vector_type(16))) float f32x16;  // 32x32 C/D frag

// 0.125 (1/sqrt(64)) * log2(e): folded into Q so softmax uses exp2
#define QSCALE 0.1803368801111244f

__device__ __forceinline__ u16 f2bf(float f) {  // RNE
  union { float f; unsigned u; } v; v.f = f;
  return (u16)((v.u + 0x7fffu + ((v.u >> 16) & 1u)) >> 16);
}
__device__ __forceinline__ float bf2f(u16 u) {
  union { unsigned u; float f; } v; v.u = ((unsigned)u) << 16; return v.f;
}
// load MFMA frag from fp32 global, converting to bf16 in-reg
__device__ __forceinline__ short8 fragf32(const float* p) {
  float4 a = reinterpret_cast<const float4*>(p)[0];
  float4 b = reinterpret_cast<const float4*>(p)[1];
  short8 h;
  h[0] = (short)f2bf(a.x); h[1] = (short)f2bf(a.y);
  h[2] = (short)f2bf(a.z); h[3] = (short)f2bf(a.w);
  h[4] = (short)f2bf(b.x); h[5] = (short)f2bf(b.y);
  h[6] = (short)f2bf(b.z); h[7] = (short)f2bf(b.w);
  return h;
}
__device__ __forceinline__ f32x16 zero16() {
  f32x16 z;
#pragma unroll
  for (int i = 0; i < 16; ++i) z[i] = 0.f;
  return z;
}
__device__ __forceinline__ unsigned cvt_pk_bf16(float lo, float hi) {
  unsigned r;
  asm("v_cvt_pk_bf16_f32 %0, %1, %2" : "=v"(r) : "v"(lo), "v"(hi));
  return r;
}
// a' = [a_lo | b_lo], b' = [a_hi | b_hi]
__device__ __forceinline__ void permlane32_swap(unsigned& a, unsigned& b) {
  asm("v_permlane32_swap_b32 %0, %1" : "+v"(a), "+v"(b));
}
// masked exp2 + li tree-sum + pack to PV A-frags for one 32-reg S half
__device__ __forceinline__ void smax_half(const f32x16& s, unsigned m32,
                                          uint4& pfa, uint4& pfb, float& li) {
  float pp[16];
#pragma unroll
  for (int r = 0; r < 16; ++r) {
    const int c = (r & 3) + 8 * (r >> 2);
    pp[r] = ((m32 >> c) & 1u) ? __builtin_amdgcn_exp2f(s[r]) : 0.f;
  }
  float t0 = (pp[0] + pp[1]) + (pp[2] + pp[3]);
  float t1 = (pp[4] + pp[5]) + (pp[6] + pp[7]);
  float t2 = (pp[8] + pp[9]) + (pp[10] + pp[11]);
  float t3 = (pp[12] + pp[13]) + (pp[14] + pp[15]);
  li += (t0 + t1) + (t2 + t3);
  unsigned wAe = cvt_pk_bf16(pp[0], pp[1]),  wBe = cvt_pk_bf16(pp[2], pp[3]);
  unsigned wAo = cvt_pk_bf16(pp[4], pp[5]),  wBo = cvt_pk_bf16(pp[6], pp[7]);
  permlane32_swap(wAe, wAo);
  permlane32_swap(wBe, wBo);
  pfa = (uint4){wAe, wBe, wAo, wBo};
  wAe = cvt_pk_bf16(pp[8], pp[9]);   wBe = cvt_pk_bf16(pp[10], pp[11]);
  wAo = cvt_pk_bf16(pp[12], pp[13]); wBo = cvt_pk_bf16(pp[14], pp[15]);
  permlane32_swap(wAe, wAo);
  permlane32_swap(wBe, wBo);
  pfb = (uint4){wAe, wBe, wAo, wBo};
}
// ABLATED variant: pack raw S (no mask test, no exp2, no li)
__device__ __forceinline__ void pack_half(const f32x16& s,
                                          uint4& pfa, uint4& pfb) {
  unsigned wAe = cvt_pk_bf16(s[0], s[1]),    wBe = cvt_pk_bf16(s[2], s[3]);
  unsigned wAo = cvt_pk_bf16(s[4], s[5]),    wBo = cvt_pk_bf16(s[6], s[7]);
  permlane32_swap(wAe, wAo);
  permlane32_swap(wBe, wBo);
  pfa = (uint4){wAe, wBe, wAo, wBo};
  wAe = cvt_pk_bf16(s[8], s[9]);   wBe = cvt_pk_bf16(s[10], s[11]);
  wAo = cvt_pk_bf16(s[12], s[13]); wBo = cvt_pk_bf16(s[14], s[15]);
  permlane32_swap(wAe, wAo);
  permlane32_swap(wBe, wBo);
  pfb = (uint4){wAe, wBe, wAo, wBo};
}

// ---------------------------------------------------------------------------
// Launch 1: prep. Blocks 0..4095: adj -> bitmask, streaming. Blocks
// 4096..4223: W fp32->bf16 (4 matrices, 2048 elems/block).
// ---------------------------------------------------------------------------
__global__ __launch_bounds__(256) void prep(
    const int* __restrict__ adj, u8* __restrict__ bmb,
    const float* __restrict__ Wq, const float* __restrict__ Wk,
    const float* __restrict__ Wv, const float* __restrict__ Wo,
    u16* __restrict__ Wqb, u16* __restrict__ Wkb,
    u16* __restrict__ Wvb, u16* __restrict__ Wob) {
  const int blk = blockIdx.x;
  if (blk < 4096) {
    const int wave = threadIdx.x >> 6, lane = threadIdx.x & 63;
    const int c0 = blk * 16 + wave * 4;  // 4 chunks of 512 keys per wave
#pragma unroll
    for (int it = 0; it < 4; ++it) {
      int c = c0 + it;
      int row = c >> 3, kb = (c & 7) * 512;
      const int* src = adj + (size_t)row * 4096 + kb + lane * 8;
      uint4 a = *reinterpret_cast<const uint4*>(src);
      uint4 b = *reinterpret_cast<const uint4*>(src + 4);
      unsigned byte = 0;
      byte |= (a.x != 0) ? 1u : 0u;
      byte |= (a.y != 0) ? 2u : 0u;
      byte |= (a.z != 0) ? 4u : 0u;
      byte |= (a.w != 0) ? 8u : 0u;
      byte |= (b.x != 0) ? 16u : 0u;
      byte |= (b.y != 0) ? 32u : 0u;
      byte |= (b.z != 0) ? 64u : 0u;
      byte |= (b.w != 0) ? 128u : 0u;
      bmb[(size_t)row * 512 + (c & 7) * 64 + lane] = (u8)byte;
    }
  } else {
    size_t base = ((size_t)(blk - 4096) * 256 + threadIdx.x) * 8;  // <262144
    int w = (int)(base >> 16);
    size_t lo = base & 65535;
    const float* src;
    u16* dst;
    if (w == 0)      { src = Wq + lo; dst = Wqb + lo; }
    else if (w == 1) { src = Wk + lo; dst = Wkb + lo; }
    else if (w == 2) { src = Wv + lo; dst = Wvb + lo; }
    else             { src = Wo + lo; dst = Wob + lo; }
    *reinterpret_cast<short8*>(dst) = fragf32(src);
  }
}

// ---------------------------------------------------------------------------
// Launch 2: fused QKV projection (MFMA). Grid (512, 3). y=0: Qb (scaled);
// y=1: Kb; y=2: Vtb[bh][d][n] (transposed output).
// ---------------------------------------------------------------------------
__global__ __launch_bounds__(256) void qkv_gemm(
    const float* __restrict__ x,
    const u16* __restrict__ Wqb, const u16* __restrict__ Wkb,
    const u16* __restrict__ Wvb,
    const float* __restrict__ bq, const float* __restrict__ bk,
    const float* __restrict__ bv,
    u16* __restrict__ Qb, u16* __restrict__ Kb, u16* __restrict__ Vtb) {
  const int tid = threadIdx.x, w = tid >> 6, lane = tid & 63;
  const int quad = lane >> 4, l15 = lane & 15;
  const int tok0 = blockIdx.x * 16;
  const int b = tok0 >> 12, nl = tok0 & 4095;
  const int ym = blockIdx.y;

  f32x4 acc[4];
#pragma unroll
  for (int i = 0; i < 4; ++i) acc[i] = (f32x4){0.f, 0.f, 0.f, 0.f};

  if (ym < 2) {
    const u16* Wb = (ym == 0) ? Wqb : Wkb;
    const float* bias = (ym == 0) ? bq : bk;
    const float scale = (ym == 0) ? QSCALE : 1.0f;
    u16* outp = (ym == 0) ? Qb : Kb;
#pragma unroll
    for (int ks = 0; ks < 8; ++ks) {
      short8 af = fragf32(x + (size_t)(tok0 + l15) * 256 + ks * 32 + quad * 8);
#pragma unroll
      for (int ns = 0; ns < 4; ++ns) {
        short8 bf = *reinterpret_cast<const short8*>(
            &Wb[(size_t)(w * 64 + ns * 16 + l15) * 256 + ks * 32 + quad * 8]);
        acc[ns] = __builtin_amdgcn_mfma_f32_16x16x32_bf16(af, bf, acc[ns], 0, 0, 0);
      }
    }
#pragma unroll
    for (int ns = 0; ns < 4; ++ns) {
      int d = ns * 16 + l15;
      float bb = bias[w * 64 + d];
#pragma unroll
      for (int r = 0; r < 4; ++r) {
        int tok = nl + quad * 4 + r;
        outp[((size_t)(b * HEADS + w) * NN + tok) * HD + d] =
            f2bf((acc[ns][r] + bb) * scale);
      }
    }
  } else {
#pragma unroll
    for (int ks = 0; ks < 8; ++ks) {
      short8 xf = fragf32(x + (size_t)(tok0 + l15) * 256 + ks * 32 + quad * 8);
#pragma unroll
      for (int ms = 0; ms < 4; ++ms) {
        short8 wf = *reinterpret_cast<const short8*>(
            &Wvb[(size_t)(w * 64 + ms * 16 + l15) * 256 + ks * 32 + quad * 8]);
        acc[ms] = __builtin_amdgcn_mfma_f32_16x16x32_bf16(wf, xf, acc[ms], 0, 0, 0);
      }
    }
#pragma unroll
    for (int ms = 0; ms < 4; ++ms) {
#pragma unroll
      for (int r = 0; r < 4; ++r) {
        int d = ms * 16 + quad * 4 + r;
        float bb = bv[w * 64 + d];
        Vtb[((size_t)((b * HEADS + w) * HD + d)) * NN + nl + l15] =
            f2bf(acc[ms][r] + bb);
      }
    }
  }
}

// ---------------------------------------------------------------------------
// Launch 3: attention (r18 structure). template<SM>: SM=1 full (correct),
// SM=0 ablated (no mask-test/exp2/li; gathers kept live via xor-keep).
// ---------------------------------------------------------------------------
#define QKT_DK2(QFA, QFB, SD)                                                  \
  { short8 ka_ = *reinterpret_cast<const short8*>(&KVs[cbq + l31 * 64 + SD]);  \
    short8 kc_ =                                                               \
        *reinterpret_cast<const short8*>(&KVs[cbq + 2048 + l31 * 64 + SD]);    \
    sA0 = __builtin_amdgcn_mfma_f32_32x32x16_bf16(ka_, QFA, sA0, 0, 0, 0);     \
    sB0 = __builtin_amdgcn_mfma_f32_32x32x16_bf16(ka_, QFB, sB0, 0, 0, 0);     \
    sA1 = __builtin_amdgcn_mfma_f32_32x32x16_bf16(kc_, QFA, sA1, 0, 0, 0);     \
    sB1 = __builtin_amdgcn_mfma_f32_32x32x16_bf16(kc_, QFB, sB1, 0, 0, 0); }

#define PV_KB2(PFA, PFB, SD)                                                   \
  { union { uint4 u; short8 s; } ua_, ub_;                                     \
    ua_.u = PFA; ub_.u = PFB;                                                  \
    short8 vf0_ =                                                              \
        *reinterpret_cast<const short8*>(&KVs[cbq + 4096 + l31 * 64 + SD]);    \
    short8 vf1_ =                                                              \
        *reinterpret_cast<const short8*>(&KVs[cbq + 6144 + l31 * 64 + SD]);    \
    OaccA0 = __builtin_amdgcn_mfma_f32_32x32x16_bf16(ua_.s, vf0_, OaccA0, 0, 0, 0); \
    OaccA1 = __builtin_amdgcn_mfma_f32_32x32x16_bf16(ua_.s, vf1_, OaccA1, 0, 0, 0); \
    OaccB0 = __builtin_amdgcn_mfma_f32_32x32x16_bf16(ub_.s, vf0_, OaccB0, 0, 0, 0); \
    OaccB1 = __builtin_amdgcn_mfma_f32_32x32x16_bf16(ub_.s, vf1_, OaccB1, 0, 0, 0); }

template <int SM>
__global__ __launch_bounds__(256, 2) void attn_mfma(
    const u16* __restrict__ Qb, const u16* __restrict__ Kb,
    const u16* __restrict__ Vtb, const u64* __restrict__ bm,
    u16* __restrict__ Opb, float* __restrict__ Lp) {
  // 2 buffers x (K tile [64][64] + V tile [64][64]) bf16, XOR-swizzled rows
  __shared__ __align__(16) u16 KVs[2 * 8192];  // 32 KB

  const int tid = threadIdx.x;
  const int wave = tid >> 6, lane = tid & 63;
  const int h5 = lane >> 5, l31 = lane & 31, l7 = lane & 7;
  const int bh = blockIdx.y, b = bh >> 2, h = bh & 3;
  const int q0 = blockIdx.x * 256 + wave * 64;
  const int quarter = blockIdx.z;
  const int key0 = quarter * 1024;
  const int NT = 16;  // 1024 keys / 64

  // Q B-frags, subtile A rows q0..q0+31, subtile B rows q0+32..q0+63
  const u16* qrA = Qb + ((size_t)bh * NN + q0 + l31) * HD + h5 * 8;
  const short8 qfA0 = *reinterpret_cast<const short8*>(qrA);
  const short8 qfA1 = *reinterpret_cast<const short8*>(qrA + 16);
  const short8 qfA2 = *reinterpret_cast<const short8*>(qrA + 32);
  const short8 qfA3 = *reinterpret_cast<const short8*>(qrA + 48);
  const u16* qrB = qrA + 32 * HD;
  const short8 qfB0 = *reinterpret_cast<const short8*>(qrB);
  const short8 qfB1 = *reinterpret_cast<const short8*>(qrB + 16);
  const short8 qfB2 = *reinterpret_cast<const short8*>(qrB + 32);
  const short8 qfB3 = *reinterpret_cast<const short8*>(qrB + 48);

  f32x16 OaccA0 = zero16(), OaccA1 = zero16();
  f32x16 OaccB0 = zero16(), OaccB1 = zero16();
  float liA = 0.f, liB = 0.f;
  u64 amKeep = 0;  // SM=0: keeps mask gathers live (rule-17)

  // frag-read slot offsets (u16 units): slot j -> ((2j+h5)^l7)*8
  int sdk[4];
#pragma unroll
  for (int j = 0; j < 4; ++j) sdk[j] = ((2 * j + h5) ^ l7) << 3;

  // staging: thread -> row tid>>2 (0..63), slots (tid&3)*2, +1 (swizzled)
  const int srow = tid >> 2;
  const int wbu0 = ((((tid & 3) * 2)     ^ (srow & 7)) << 3) + srow * 64;
  const int wbu1 = ((((tid & 3) * 2 + 1) ^ (srow & 7)) << 3) + srow * 64;

  const u16* kbase = Kb + (size_t)bh * NN * HD + (size_t)key0 * HD;
  const u16* vbase = Vtb + (size_t)bh * HD * NN + key0;
  const u64* bmrA = bm + ((size_t)b * NN + q0 + l31) * 64 + quarter * 16;
  const u64* bmrB = bmrA + (size_t)32 * 64;

  uint4 k0, k1, v0, v1;
  {  // tile 0 load
    const uint4* kp = reinterpret_cast<const uint4*>(kbase) + tid * 2;
    k0 = kp[0]; k1 = kp[1];
    const u16* vp = vbase + (size_t)srow * NN + (tid & 3) * 16;
    v0 = *reinterpret_cast<const uint4*>(vp);
    v1 = *reinterpret_cast<const uint4*>(vp + 8);
  }
  // stage tile 0 into buffer 0
  *reinterpret_cast<uint4*>(&KVs[wbu0]) = k0;
  *reinterpret_cast<uint4*>(&KVs[wbu1]) = k1;
  *reinterpret_cast<uint4*>(&KVs[4096 + wbu0]) = v0;
  *reinterpret_cast<uint4*>(&KVs[4096 + wbu1]) = v1;
  {  // prefetch tile 1
    const uint4* kp = reinterpret_cast<const uint4*>(kbase + 4096) + tid * 2;
    k0 = kp[0]; k1 = kp[1];
    const u16* vp = vbase + (size_t)srow * NN + 64 + (tid & 3) * 16;
    v0 = *reinterpret_cast<const uint4*>(vp);
    v1 = *reinterpret_cast<const uint4*>(vp + 8);
  }
  u64 amA_c = bmrA[0], amB_c = bmrB[0];

  for (int mt = 0; mt < NT; ++mt) {
    __syncthreads();  // buf[mt&1] staged by all waves; prev-tile reads done
    const u64 amA = amA_c, amB = amB_c;
    if (mt + 1 < NT) { amA_c = bmrA[mt + 1]; amB_c = bmrB[mt + 1]; }
    const int cbq = (mt & 1) * 8192;  // current buffer base (u16)

    // ---- QK^T swapped, both subtiles share every K fragment ----
    f32x16 sA0 = zero16(), sA1 = zero16();
    f32x16 sB0 = zero16(), sB1 = zero16();
    __builtin_amdgcn_s_setprio(1);
    QKT_DK2(qfA0, qfB0, sdk[0]);
    QKT_DK2(qfA1, qfB1, sdk[1]);
    QKT_DK2(qfA2, qfB2, sdk[2]);
    QKT_DK2(qfA3, qfB3, sdk[3]);
    __builtin_amdgcn_s_setprio(0);

    uint4 pA0, pA1, pA2, pA3, pB0, pB1, pB2, pB3;
    if constexpr (SM) {
      // lane's q-rows: A = q0+l31, B = q0+32+l31. Pre-shift masks by 4*h5.
      const u64 ashA = amA >> (4 * h5);
      const u64 ashB = amB >> (4 * h5);
      smax_half(sA0, (unsigned)ashA, pA0, pA1, liA);
      smax_half(sA1, (unsigned)(ashA >> 32), pA2, pA3, liA);
      smax_half(sB0, (unsigned)ashB, pB0, pB1, liB);
      smax_half(sB1, (unsigned)(ashB >> 32), pB2, pB3, liB);
    } else {
      amKeep ^= amA ^ amB;  // keep gathers live, ~4 VALU ops
      pack_half(sA0, pA0, pA1);
      pack_half(sA1, pA2, pA3);
      pack_half(sB0, pB0, pB1);
      pack_half(sB1, pB2, pB3);
    }

    // ---- PV, both subtiles share every V fragment ----
    __builtin_amdgcn_s_setprio(1);
    PV_KB2(pA0, pB0, sdk[0]);
    PV_KB2(pA1, pB1, sdk[1]);
    PV_KB2(pA2, pB2, sdk[2]);
    PV_KB2(pA3, pB3, sdk[3]);
    __builtin_amdgcn_s_setprio(0);

    // ---- stage next tile into alt buffer; prefetch tile mt+2 ----
    if (mt + 1 < NT) {
      const int nb = ((mt + 1) & 1) * 8192;
      *reinterpret_cast<uint4*>(&KVs[nb + wbu0]) = k0;
      *reinterpret_cast<uint4*>(&KVs[nb + wbu1]) = k1;
      *reinterpret_cast<uint4*>(&KVs[nb + 4096 + wbu0]) = v0;
      *reinterpret_cast<uint4*>(&KVs[nb + 4096 + wbu1]) = v1;
      if (mt + 2 < NT) {
        const uint4* kp =
            reinterpret_cast<const uint4*>(kbase + (size_t)(mt + 2) * 4096) + tid * 2;
        k0 = kp[0]; k1 = kp[1];
        const u16* vp = vbase + (size_t)srow * NN + (mt + 2) * 64 + (tid & 3) * 16;
        v0 = *reinterpret_cast<const uint4*>(vp);
        v1 = *reinterpret_cast<const uint4*>(vp + 8);
      }
    }
  }

  // epilogue: Oacc reg r -> O[q + (r&3)+8*(r>>2)+4*h5][d-half + l31]
  u16* ob = Opb + (size_t)(quarter * NB + b) * NN * CDIM;
#pragma unroll
  for (int r = 0; r < 16; ++r) {
    const int tokA = q0 + (r & 3) + 8 * (r >> 2) + 4 * h5;
    u16* orA = ob + (size_t)tokA * CDIM + h * HD;
    orA[l31] = f2bf(OaccA0[r]);
    orA[32 + l31] = f2bf(OaccA1[r]);
    u16* orB = orA + (size_t)32 * CDIM;
    orB[l31] = f2bf(OaccB0[r]);
    orB[32 + l31] = f2bf(OaccB1[r]);
  }
  {  // li: combine h5 halves (lane and lane^32 hold complementary keys)
    unsigned a0 = __float_as_uint(liA), a1 = a0;
    permlane32_swap(a0, a1);
    float liAf = __uint_as_float(a0) + __uint_as_float(a1);
    unsigned b0 = __float_as_uint(liB), b1 = b0;
    permlane32_swap(b0, b1);
    float liBf = __uint_as_float(b0) + __uint_as_float(b1);
    if constexpr (!SM) {  // unprovable guard keeps amKeep (and gathers) live;
      if (amKeep == 0x1234567887654321ull) liAf += 1.f;  // ~never taken
    }
    if (lane < 32) {
      float* lrow = Lp + ((size_t)quarter * 8 + bh) * NN;
      lrow[q0 + lane] = liAf;
      lrow[q0 + 32 + lane] = liBf;
    }
  }
}

// ---------------------------------------------------------------------------
// Launch 4: combine quarters + output projection (MFMA) + LayerNorm.
// ---------------------------------------------------------------------------
__global__ __launch_bounds__(256) void comb_oproj(
    const u16* __restrict__ Opb, const float* __restrict__ Lp,
    const u16* __restrict__ Wob, const float* __restrict__ bo,
    const float* __restrict__ gamma, const float* __restrict__ beta,
    float* __restrict__ out) {
  __shared__ u16 As[16 * 264];
  __shared__ float ys[16][264];
  __shared__ float linv[64];
  const int tid = threadIdx.x, w = tid >> 6, lane = tid & 63;
  const int quad = lane >> 4, l15 = lane & 15;
  const int tok0 = blockIdx.x * 16;
  const int b = tok0 >> 12, nl = tok0 & 4095;

  if (tid < 64) {
    int tokr = tid >> 2, hh = tid & 3;
    int bh = b * 4 + hh;
    int n = nl + tokr;
    float s = 0.f;
#pragma unroll
    for (int q = 0; q < 4; ++q)
      s += Lp[((size_t)q * 8 + bh) * NN + n];
    linv[tokr * 4 + hh] = (s > 0.f) ? (1.f / s) : 0.f;
  }
  __syncthreads();

  {
    int tokr = tid >> 4, ch0 = (tid & 15) * 16;
    size_t base = ((size_t)b * NN + nl + tokr) * CDIM + ch0;
    float inv = linv[tokr * 4 + (ch0 >> 6)];
    float acc16[16];
#pragma unroll
    for (int i = 0; i < 16; ++i) acc16[i] = 0.f;
#pragma unroll
    for (int q = 0; q < 4; ++q) {
      size_t qb = (size_t)q * 2097152 + base;
      uint4 a0 = *reinterpret_cast<const uint4*>(Opb + qb);
      uint4 a1 = *reinterpret_cast<const uint4*>(Opb + qb + 8);
      unsigned wa[8] = {a0.x, a0.y, a0.z, a0.w, a1.x, a1.y, a1.z, a1.w};
#pragma unroll
      for (int i = 0; i < 8; ++i) {
        acc16[2 * i]     += bf2f((u16)(wa[i] & 0xffffu));
        acc16[2 * i + 1] += bf2f((u16)(wa[i] >> 16));
      }
    }
    u16 ov[16];
#pragma unroll
    for (int i = 0; i < 16; ++i) ov[i] = f2bf(acc16[i] * inv);
    u16* dst = &As[tokr * 264 + ch0];
    *reinterpret_cast<uint4*>(dst) = *reinterpret_cast<uint4*>(ov);
    *reinterpret_cast<uint4*>(dst + 8) = *reinterpret_cast<uint4*>(ov + 8);
  }
  __syncthreads();

  f32x4 acc[4];
#pragma unroll
  for (int i = 0; i < 4; ++i) acc[i] = (f32x4){0.f, 0.f, 0.f, 0.f};
#pragma unroll
  for (int ks = 0; ks < 8; ++ks) {
    short8 af = *reinterpret_cast<const short8*>(&As[l15 * 264 + ks * 32 + quad * 8]);
#pragma unroll
    for (int ns = 0; ns < 4; ++ns) {
      short8 bf = *reinterpret_cast<const short8*>(
          &Wob[(size_t)(w * 64 + ns * 16 + l15) * 256 + ks * 32 + quad * 8]);
      acc[ns] = __builtin_amdgcn_mfma_f32_16x16x32_bf16(af, bf, acc[ns], 0, 0, 0);
    }
  }

#pragma unroll
  for (int ns = 0; ns < 4; ++ns) {
    int ch = w * 64 + ns * 16 + l15;
    float bb = bo[ch];
#pragma unroll
    for (int r = 0; r < 4; ++r) ys[quad * 4 + r][ch] = acc[ns][r] + bb;
  }
  __syncthreads();

  float g[4], bt[4];
#pragma unroll
  for (int i = 0; i < 4; ++i) {
    g[i] = gamma[lane + i * 64];
    bt[i] = beta[lane + i * 64];
  }
#pragma unroll
  for (int rr = 0; rr < 4; ++rr) {
    int r = w * 4 + rr;
    float v[4], s = 0.f, s2 = 0.f;
#pragma unroll
    for (int i = 0; i < 4; ++i) {
      v[i] = ys[r][lane + i * 64];
      s += v[i];
      s2 = fmaf(v[i], v[i], s2);
    }
#pragma unroll
    for (int off = 32; off > 0; off >>= 1) {
      s += __shfl_xor(s, off, 64);
      s2 += __shfl_xor(s2, off, 64);
    }
    float mu = s * (1.f / 256.f);
    float rs = rsqrtf(s2 * (1.f / 256.f) - mu * mu + 1e-5f);
    float* orow = out + (size_t)(tok0 + r) * 256;
#pragma unroll
    for (int i = 0; i < 4; ++i)
      orow[lane + i * 64] = (v[i] - mu) * rs * g[i] + bt[i];
  }
}

// ---------------------------------------------------------------------------
extern "C" void kernel_launch(void* const* d_in, const int* in_sizes, int n_in,
                              void* d_out, int out_size, void* d_ws, size_t ws_size,
                              hipStream_t stream) {
  const float* x     = (const float*)d_in[0];
  const int*   adj   = (const int*)d_in[1];
  const float* Wq    = (const float*)d_in[2];
  const float* bq    = (const float*)d_in[3];
  const float* Wk    = (const float*)d_in[4];
  const float* bk    = (const float*)d_in[5];
  const float* Wv    = (const float*)d_in[6];
  const float* bv    = (const float*)d_in[7];
  const float* Wo    = (const float*)d_in[8];
  const float* bo    = (const float*)d_in[9];
  const float* gamma = (const float*)d_in[10];
  const float* beta  = (const float*)d_in[11];
  float* out = (float*)d_out;

  const size_t PER = (size_t)NB * HEADS * NN * HD;  // 2,097,152
  u16* Wqb = (u16*)d_ws;                 // 65,536 each
  u16* Wkb = Wqb + 65536;
  u16* Wvb = Wkb + 65536;
  u16* Wob = Wvb + 65536;
  u64* bmp = (u64*)(Wob + 65536);        // 524,288 u64 (4 MB), 8B-aligned
  u16* Qb  = (u16*)(bmp + 524288);
  u16* Kb  = Qb + PER;
  u16* Vtb = Kb + PER;
  u16* Opb = Vtb + PER;                  // 4 x PER bf16 (quarter partials)
  float* Lp = (float*)(Opb + 4 * PER);   // 131,072 fp32

  const size_t NEED = (size_t)((u16*)(Lp + 131072) - (u16*)d_ws) * sizeof(u16);
  if (ws_size < NEED) return;

  prep<<<dim3(4224), dim3(256), 0, stream>>>(
      adj, (u8*)bmp, Wq, Wk, Wv, Wo, Wqb, Wkb, Wvb, Wob);

  qkv_gemm<<<dim3(512, 3), dim3(256), 0, stream>>>(
      x, Wqb, Wkb, Wvb, bq, bk, bv, Qb, Kb, Vtb);

  // r20 ABLATION: 2x noSM variant then 1x full. Full overwrites every
  // Opb/Lp byte -> final state correct. (dur - 307.6)/2 = noSM launch cost;
  // compare vs 46.2 (r19 full-launch cost).
  attn_mfma<0><<<dim3(NN / 256, NB * HEADS, 4), dim3(256), 0, stream>>>(
      Qb, Kb, Vtb, bmp, Opb, Lp);
  attn_mfma<0><<<dim3(NN / 256, NB * HEADS, 4), dim3(256), 0, stream>>>(
      Qb, Kb, Vtb, bmp, Opb, Lp);
  attn_mfma<1><<<dim3(NN / 256, NB * HEADS, 4), dim3(256), 0, stream>>>(
      Qb, Kb, Vtb, bmp, Opb, Lp);

  comb_oproj<<<dim3((NB * NN) / 16), dim3(256), 0, stream>>>(
      Opb, Lp, Wob, bo, gamma, beta, out);
}

// Round 8
// 307.543 us; speedup vs baseline: 1.3003x; 1.2172x over previous
//
#include <hip/hip_runtime.h>
#include <stdint.h>

// GraphAttention: B=2, N=4096, C=256, H=4, D=64. Inputs fp32, adj int32,
// OUTPUT FP32 (proven r6/r7). Threshold = 2% of ref absmax = 0.0609.
// r14: attn 32x32x16 swapped-QK^T. 353.6 -> 317.7.
// r15: z=4 + setprio -> 309.9.  r16/r17: 2-tile pipeline ~0.  r18: 64q/wave ~0.
// r19: 3x-probe: attn = 46.2us.  r20: noSM ablation: 33.4us -> softmax VALU
//      = 12.8us serial; noSM floor 33.4 >> compute floor ~15 => ~18us is HBM
//      K/V duplication across XCDs (16 sharers of each K/V panel round-robin
//      onto 8 different L2s => ~140MB fetch/launch).
// r21: XCD-aware swizzle (T1): 1-D grid 512, bh = fid&7 => all blocks of a
//      head land on one XCD (fid%8 mapping); per-XCD set ~3.5MB fits 4MB L2.
//      Unique HBM ~28MB. Single attn launch restored. Inner loop = r18.
#define CDIM 256
#define HEADS 4
#define HD 64
#define NB 2
#define NN 4096

typedef unsigned short u16;
typedef unsigned char u8;
typedef unsigned long long u64;
typedef __attribute__((ext_vector_type(8))) short short8;   // bf16x8 frag
typedef __attribute__((ext_vector_type(4))) float f32x4;    // 16x16 C/D frag
typedef __attribute__((ext_vector_type(16))) float f32x16;  // 32x32 C/D frag

// 0.125 (1/sqrt(64)) * log2(e): folded into Q so softmax uses exp2
#define QSCALE 0.1803368801111244f

__device__ __forceinline__ u16 f2bf(float f) {  // RNE
  union { float f; unsigned u; } v; v.f = f;
  return (u16)((v.u + 0x7fffu + ((v.u >> 16) & 1u)) >> 16);
}
__device__ __forceinline__ float bf2f(u16 u) {
  union { unsigned u; float f; } v; v.u = ((unsigned)u) << 16; return v.f;
}
// load MFMA frag from fp32 global, converting to bf16 in-reg
__device__ __forceinline__ short8 fragf32(const float* p) {
  float4 a = reinterpret_cast<const float4*>(p)[0];
  float4 b = reinterpret_cast<const float4*>(p)[1];
  short8 h;
  h[0] = (short)f2bf(a.x); h[1] = (short)f2bf(a.y);
  h[2] = (short)f2bf(a.z); h[3] = (short)f2bf(a.w);
  h[4] = (short)f2bf(b.x); h[5] = (short)f2bf(b.y);
  h[6] = (short)f2bf(b.z); h[7] = (short)f2bf(b.w);
  return h;
}
__device__ __forceinline__ f32x16 zero16() {
  f32x16 z;
#pragma unroll
  for (int i = 0; i < 16; ++i) z[i] = 0.f;
  return z;
}
__device__ __forceinline__ unsigned cvt_pk_bf16(float lo, float hi) {
  unsigned r;
  asm("v_cvt_pk_bf16_f32 %0, %1, %2" : "=v"(r) : "v"(lo), "v"(hi));
  return r;
}
// a' = [a_lo | b_lo], b' = [a_hi | b_hi]
__device__ __forceinline__ void permlane32_swap(unsigned& a, unsigned& b) {
  asm("v_permlane32_swap_b32 %0, %1" : "+v"(a), "+v"(b));
}
// masked exp2 + li tree-sum + pack to PV A-frags for one 32-reg S half
__device__ __forceinline__ void smax_half(const f32x16& s, unsigned m32,
                                          uint4& pfa, uint4& pfb, float& li) {
  float pp[16];
#pragma unroll
  for (int r = 0; r < 16; ++r) {
    const int c = (r & 3) + 8 * (r >> 2);
    pp[r] = ((m32 >> c) & 1u) ? __builtin_amdgcn_exp2f(s[r]) : 0.f;
  }
  float t0 = (pp[0] + pp[1]) + (pp[2] + pp[3]);
  float t1 = (pp[4] + pp[5]) + (pp[6] + pp[7]);
  float t2 = (pp[8] + pp[9]) + (pp[10] + pp[11]);
  float t3 = (pp[12] + pp[13]) + (pp[14] + pp[15]);
  li += (t0 + t1) + (t2 + t3);
  unsigned wAe = cvt_pk_bf16(pp[0], pp[1]),  wBe = cvt_pk_bf16(pp[2], pp[3]);
  unsigned wAo = cvt_pk_bf16(pp[4], pp[5]),  wBo = cvt_pk_bf16(pp[6], pp[7]);
  permlane32_swap(wAe, wAo);
  permlane32_swap(wBe, wBo);
  pfa = (uint4){wAe, wBe, wAo, wBo};
  wAe = cvt_pk_bf16(pp[8], pp[9]);   wBe = cvt_pk_bf16(pp[10], pp[11]);
  wAo = cvt_pk_bf16(pp[12], pp[13]); wBo = cvt_pk_bf16(pp[14], pp[15]);
  permlane32_swap(wAe, wAo);
  permlane32_swap(wBe, wBo);
  pfb = (uint4){wAe, wBe, wAo, wBo};
}

// ---------------------------------------------------------------------------
// Launch 1: prep. Blocks 0..4095: adj -> bitmask, streaming. Blocks
// 4096..4223: W fp32->bf16 (4 matrices, 2048 elems/block).
// ---------------------------------------------------------------------------
__global__ __launch_bounds__(256) void prep(
    const int* __restrict__ adj, u8* __restrict__ bmb,
    const float* __restrict__ Wq, const float* __restrict__ Wk,
    const float* __restrict__ Wv, const float* __restrict__ Wo,
    u16* __restrict__ Wqb, u16* __restrict__ Wkb,
    u16* __restrict__ Wvb, u16* __restrict__ Wob) {
  const int blk = blockIdx.x;
  if (blk < 4096) {
    const int wave = threadIdx.x >> 6, lane = threadIdx.x & 63;
    const int c0 = blk * 16 + wave * 4;  // 4 chunks of 512 keys per wave
#pragma unroll
    for (int it = 0; it < 4; ++it) {
      int c = c0 + it;
      int row = c >> 3, kb = (c & 7) * 512;
      const int* src = adj + (size_t)row * 4096 + kb + lane * 8;
      uint4 a = *reinterpret_cast<const uint4*>(src);
      uint4 b = *reinterpret_cast<const uint4*>(src + 4);
      unsigned byte = 0;
      byte |= (a.x != 0) ? 1u : 0u;
      byte |= (a.y != 0) ? 2u : 0u;
      byte |= (a.z != 0) ? 4u : 0u;
      byte |= (a.w != 0) ? 8u : 0u;
      byte |= (b.x != 0) ? 16u : 0u;
      byte |= (b.y != 0) ? 32u : 0u;
      byte |= (b.z != 0) ? 64u : 0u;
      byte |= (b.w != 0) ? 128u : 0u;
      bmb[(size_t)row * 512 + (c & 7) * 64 + lane] = (u8)byte;
    }
  } else {
    size_t base = ((size_t)(blk - 4096) * 256 + threadIdx.x) * 8;  // <262144
    int w = (int)(base >> 16);
    size_t lo = base & 65535;
    const float* src;
    u16* dst;
    if (w == 0)      { src = Wq + lo; dst = Wqb + lo; }
    else if (w == 1) { src = Wk + lo; dst = Wkb + lo; }
    else if (w == 2) { src = Wv + lo; dst = Wvb + lo; }
    else             { src = Wo + lo; dst = Wob + lo; }
    *reinterpret_cast<short8*>(dst) = fragf32(src);
  }
}

// ---------------------------------------------------------------------------
// Launch 2: fused QKV projection (MFMA). Grid (512, 3). y=0: Qb (scaled);
// y=1: Kb; y=2: Vtb[bh][d][n] (transposed output).
// ---------------------------------------------------------------------------
__global__ __launch_bounds__(256) void qkv_gemm(
    const float* __restrict__ x,
    const u16* __restrict__ Wqb, const u16* __restrict__ Wkb,
    const u16* __restrict__ Wvb,
    const float* __restrict__ bq, const float* __restrict__ bk,
    const float* __restrict__ bv,
    u16* __restrict__ Qb, u16* __restrict__ Kb, u16* __restrict__ Vtb) {
  const int tid = threadIdx.x, w = tid >> 6, lane = tid & 63;
  const int quad = lane >> 4, l15 = lane & 15;
  const int tok0 = blockIdx.x * 16;
  const int b = tok0 >> 12, nl = tok0 & 4095;
  const int ym = blockIdx.y;

  f32x4 acc[4];
#pragma unroll
  for (int i = 0; i < 4; ++i) acc[i] = (f32x4){0.f, 0.f, 0.f, 0.f};

  if (ym < 2) {
    const u16* Wb = (ym == 0) ? Wqb : Wkb;
    const float* bias = (ym == 0) ? bq : bk;
    const float scale = (ym == 0) ? QSCALE : 1.0f;
    u16* outp = (ym == 0) ? Qb : Kb;
#pragma unroll
    for (int ks = 0; ks < 8; ++ks) {
      short8 af = fragf32(x + (size_t)(tok0 + l15) * 256 + ks * 32 + quad * 8);
#pragma unroll
      for (int ns = 0; ns < 4; ++ns) {
        short8 bf = *reinterpret_cast<const short8*>(
            &Wb[(size_t)(w * 64 + ns * 16 + l15) * 256 + ks * 32 + quad * 8]);
        acc[ns] = __builtin_amdgcn_mfma_f32_16x16x32_bf16(af, bf, acc[ns], 0, 0, 0);
      }
    }
#pragma unroll
    for (int ns = 0; ns < 4; ++ns) {
      int d = ns * 16 + l15;
      float bb = bias[w * 64 + d];
#pragma unroll
      for (int r = 0; r < 4; ++r) {
        int tok = nl + quad * 4 + r;
        outp[((size_t)(b * HEADS + w) * NN + tok) * HD + d] =
            f2bf((acc[ns][r] + bb) * scale);
      }
    }
  } else {
#pragma unroll
    for (int ks = 0; ks < 8; ++ks) {
      short8 xf = fragf32(x + (size_t)(tok0 + l15) * 256 + ks * 32 + quad * 8);
#pragma unroll
      for (int ms = 0; ms < 4; ++ms) {
        short8 wf = *reinterpret_cast<const short8*>(
            &Wvb[(size_t)(w * 64 + ms * 16 + l15) * 256 + ks * 32 + quad * 8]);
        acc[ms] = __builtin_amdgcn_mfma_f32_16x16x32_bf16(wf, xf, acc[ms], 0, 0, 0);
      }
    }
#pragma unroll
    for (int ms = 0; ms < 4; ++ms) {
#pragma unroll
      for (int r = 0; r < 4; ++r) {
        int d = ms * 16 + quad * 4 + r;
        float bb = bv[w * 64 + d];
        Vtb[((size_t)((b * HEADS + w) * HD + d)) * NN + nl + l15] =
            f2bf(acc[ms][r] + bb);
      }
    }
  }
}

// ---------------------------------------------------------------------------
// Launch 3: attention (r18 inner loop), 1-D grid 512 with XCD-aware decode:
// fid = blockIdx.x; bh = fid&7 (=> XCD under fid%8 round-robin), x = (fid>>3)
// &15, quarter = fid>>7. All 64 blocks of a head share one XCD's L2; per-XCD
// working set (K 1MB + V 1MB + Q 0.5MB + bm ~1MB) fits 4MB L2.
// ---------------------------------------------------------------------------
#define QKT_DK2(QFA, QFB, SD)                                                  \
  { short8 ka_ = *reinterpret_cast<const short8*>(&KVs[cbq + l31 * 64 + SD]);  \
    short8 kc_ =                                                               \
        *reinterpret_cast<const short8*>(&KVs[cbq + 2048 + l31 * 64 + SD]);    \
    sA0 = __builtin_amdgcn_mfma_f32_32x32x16_bf16(ka_, QFA, sA0, 0, 0, 0);     \
    sB0 = __builtin_amdgcn_mfma_f32_32x32x16_bf16(ka_, QFB, sB0, 0, 0, 0);     \
    sA1 = __builtin_amdgcn_mfma_f32_32x32x16_bf16(kc_, QFA, sA1, 0, 0, 0);     \
    sB1 = __builtin_amdgcn_mfma_f32_32x32x16_bf16(kc_, QFB, sB1, 0, 0, 0); }

#define PV_KB2(PFA, PFB, SD)                                                   \
  { union { uint4 u; short8 s; } ua_, ub_;                                     \
    ua_.u = PFA; ub_.u = PFB;                                                  \
    short8 vf0_ =                                                              \
        *reinterpret_cast<const short8*>(&KVs[cbq + 4096 + l31 * 64 + SD]);    \
    short8 vf1_ =                                                              \
        *reinterpret_cast<const short8*>(&KVs[cbq + 6144 + l31 * 64 + SD]);    \
    OaccA0 = __builtin_amdgcn_mfma_f32_32x32x16_bf16(ua_.s, vf0_, OaccA0, 0, 0, 0); \
    OaccA1 = __builtin_amdgcn_mfma_f32_32x32x16_bf16(ua_.s, vf1_, OaccA1, 0, 0, 0); \
    OaccB0 = __builtin_amdgcn_mfma_f32_32x32x16_bf16(ub_.s, vf0_, OaccB0, 0, 0, 0); \
    OaccB1 = __builtin_amdgcn_mfma_f32_32x32x16_bf16(ub_.s, vf1_, OaccB1, 0, 0, 0); }

__global__ __launch_bounds__(256, 2) void attn_mfma(
    const u16* __restrict__ Qb, const u16* __restrict__ Kb,
    const u16* __restrict__ Vtb, const u64* __restrict__ bm,
    u16* __restrict__ Opb, float* __restrict__ Lp) {
  // 2 buffers x (K tile [64][64] + V tile [64][64]) bf16, XOR-swizzled rows
  __shared__ __align__(16) u16 KVs[2 * 8192];  // 32 KB

  const int tid = threadIdx.x;
  const int wave = tid >> 6, lane = tid & 63;
  const int h5 = lane >> 5, l31 = lane & 31, l7 = lane & 7;
  // XCD-aware decode (r21): bh in low 3 bits pins each head to one XCD
  const int fid = blockIdx.x;
  const int bh = fid & 7, b = bh >> 2, h = bh & 3;
  const int xblk = (fid >> 3) & 15;
  const int quarter = fid >> 7;
  const int q0 = xblk * 256 + wave * 64;
  const int key0 = quarter * 1024;
  const int NT = 16;  // 1024 keys / 64

  // Q B-frags, subtile A rows q0..q0+31, subtile B rows q0+32..q0+63
  const u16* qrA = Qb + ((size_t)bh * NN + q0 + l31) * HD + h5 * 8;
  const short8 qfA0 = *reinterpret_cast<const short8*>(qrA);
  const short8 qfA1 = *reinterpret_cast<const short8*>(qrA + 16);
  const short8 qfA2 = *reinterpret_cast<const short8*>(qrA + 32);
  const short8 qfA3 = *reinterpret_cast<const short8*>(qrA + 48);
  const u16* qrB = qrA + 32 * HD;
  const short8 qfB0 = *reinterpret_cast<const short8*>(qrB);
  const short8 qfB1 = *reinterpret_cast<const short8*>(qrB + 16);
  const short8 qfB2 = *reinterpret_cast<const short8*>(qrB + 32);
  const short8 qfB3 = *reinterpret_cast<const short8*>(qrB + 48);

  f32x16 OaccA0 = zero16(), OaccA1 = zero16();
  f32x16 OaccB0 = zero16(), OaccB1 = zero16();
  float liA = 0.f, liB = 0.f;

  // frag-read slot offsets (u16 units): slot j -> ((2j+h5)^l7)*8
  int sdk[4];
#pragma unroll
  for (int j = 0; j < 4; ++j) sdk[j] = ((2 * j + h5) ^ l7) << 3;

  // staging: thread -> row tid>>2 (0..63), slots (tid&3)*2, +1 (swizzled)
  const int srow = tid >> 2;
  const int wbu0 = ((((tid & 3) * 2)     ^ (srow & 7)) << 3) + srow * 64;
  const int wbu1 = ((((tid & 3) * 2 + 1) ^ (srow & 7)) << 3) + srow * 64;

  const u16* kbase = Kb + (size_t)bh * NN * HD + (size_t)key0 * HD;
  const u16* vbase = Vtb + (size_t)bh * HD * NN + key0;
  const u64* bmrA = bm + ((size_t)b * NN + q0 + l31) * 64 + quarter * 16;
  const u64* bmrB = bmrA + (size_t)32 * 64;

  uint4 k0, k1, v0, v1;
  {  // tile 0 load
    const uint4* kp = reinterpret_cast<const uint4*>(kbase) + tid * 2;
    k0 = kp[0]; k1 = kp[1];
    const u16* vp = vbase + (size_t)srow * NN + (tid & 3) * 16;
    v0 = *reinterpret_cast<const uint4*>(vp);
    v1 = *reinterpret_cast<const uint4*>(vp + 8);
  }
  // stage tile 0 into buffer 0
  *reinterpret_cast<uint4*>(&KVs[wbu0]) = k0;
  *reinterpret_cast<uint4*>(&KVs[wbu1]) = k1;
  *reinterpret_cast<uint4*>(&KVs[4096 + wbu0]) = v0;
  *reinterpret_cast<uint4*>(&KVs[4096 + wbu1]) = v1;
  {  // prefetch tile 1
    const uint4* kp = reinterpret_cast<const uint4*>(kbase + 4096) + tid * 2;
    k0 = kp[0]; k1 = kp[1];
    const u16* vp = vbase + (size_t)srow * NN + 64 + (tid & 3) * 16;
    v0 = *reinterpret_cast<const uint4*>(vp);
    v1 = *reinterpret_cast<const uint4*>(vp + 8);
  }
  u64 amA_c = bmrA[0], amB_c = bmrB[0];

  for (int mt = 0; mt < NT; ++mt) {
    __syncthreads();  // buf[mt&1] staged by all waves; prev-tile reads done
    const u64 amA = amA_c, amB = amB_c;
    if (mt + 1 < NT) { amA_c = bmrA[mt + 1]; amB_c = bmrB[mt + 1]; }
    const int cbq = (mt & 1) * 8192;  // current buffer base (u16)

    // ---- QK^T swapped, both subtiles share every K fragment ----
    f32x16 sA0 = zero16(), sA1 = zero16();
    f32x16 sB0 = zero16(), sB1 = zero16();
    __builtin_amdgcn_s_setprio(1);
    QKT_DK2(qfA0, qfB0, sdk[0]);
    QKT_DK2(qfA1, qfB1, sdk[1]);
    QKT_DK2(qfA2, qfB2, sdk[2]);
    QKT_DK2(qfA3, qfB3, sdk[3]);
    __builtin_amdgcn_s_setprio(0);

    // lane's q-rows: A = q0+l31, B = q0+32+l31. Pre-shift masks by 4*h5.
    const u64 ashA = amA >> (4 * h5);
    const u64 ashB = amB >> (4 * h5);

    uint4 pA0, pA1, pA2, pA3, pB0, pB1, pB2, pB3;
    smax_half(sA0, (unsigned)ashA, pA0, pA1, liA);
    smax_half(sA1, (unsigned)(ashA >> 32), pA2, pA3, liA);
    smax_half(sB0, (unsigned)ashB, pB0, pB1, liB);
    smax_half(sB1, (unsigned)(ashB >> 32), pB2, pB3, liB);

    // ---- PV, both subtiles share every V fragment ----
    __builtin_amdgcn_s_setprio(1);
    PV_KB2(pA0, pB0, sdk[0]);
    PV_KB2(pA1, pB1, sdk[1]);
    PV_KB2(pA2, pB2, sdk[2]);
    PV_KB2(pA3, pB3, sdk[3]);
    __builtin_amdgcn_s_setprio(0);

    // ---- stage next tile into alt buffer; prefetch tile mt+2 ----
    if (mt + 1 < NT) {
      const int nb = ((mt + 1) & 1) * 8192;
      *reinterpret_cast<uint4*>(&KVs[nb + wbu0]) = k0;
      *reinterpret_cast<uint4*>(&KVs[nb + wbu1]) = k1;
      *reinterpret_cast<uint4*>(&KVs[nb + 4096 + wbu0]) = v0;
      *reinterpret_cast<uint4*>(&KVs[nb + 4096 + wbu1]) = v1;
      if (mt + 2 < NT) {
        const uint4* kp =
            reinterpret_cast<const uint4*>(kbase + (size_t)(mt + 2) * 4096) + tid * 2;
        k0 = kp[0]; k1 = kp[1];
        const u16* vp = vbase + (size_t)srow * NN + (mt + 2) * 64 + (tid & 3) * 16;
        v0 = *reinterpret_cast<const uint4*>(vp);
        v1 = *reinterpret_cast<const uint4*>(vp + 8);
      }
    }
  }

  // epilogue: Oacc reg r -> O[q + (r&3)+8*(r>>2)+4*h5][d-half + l31]
  u16* ob = Opb + (size_t)(quarter * NB + b) * NN * CDIM;
#pragma unroll
  for (int r = 0; r < 16; ++r) {
    const int tokA = q0 + (r & 3) + 8 * (r >> 2) + 4 * h5;
    u16* orA = ob + (size_t)tokA * CDIM + h * HD;
    orA[l31] = f2bf(OaccA0[r]);
    orA[32 + l31] = f2bf(OaccA1[r]);
    u16* orB = orA + (size_t)32 * CDIM;
    orB[l31] = f2bf(OaccB0[r]);
    orB[32 + l31] = f2bf(OaccB1[r]);
  }
  {  // li: combine h5 halves (lane and lane^32 hold complementary keys)
    unsigned a0 = __float_as_uint(liA), a1 = a0;
    permlane32_swap(a0, a1);
    float liAf = __uint_as_float(a0) + __uint_as_float(a1);
    unsigned b0 = __float_as_uint(liB), b1 = b0;
    permlane32_swap(b0, b1);
    float liBf = __uint_as_float(b0) + __uint_as_float(b1);
    if (lane < 32) {
      float* lrow = Lp + ((size_t)quarter * 8 + bh) * NN;
      lrow[q0 + lane] = liAf;
      lrow[q0 + 32 + lane] = liBf;
    }
  }
}

// ---------------------------------------------------------------------------
// Launch 4: combine quarters + output projection (MFMA) + LayerNorm.
// ---------------------------------------------------------------------------
__global__ __launch_bounds__(256) void comb_oproj(
    const u16* __restrict__ Opb, const float* __restrict__ Lp,
    const u16* __restrict__ Wob, const float* __restrict__ bo,
    const float* __restrict__ gamma, const float* __restrict__ beta,
    float* __restrict__ out) {
  __shared__ u16 As[16 * 264];
  __shared__ float ys[16][264];
  __shared__ float linv[64];
  const int tid = threadIdx.x, w = tid >> 6, lane = tid & 63;
  const int quad = lane >> 4, l15 = lane & 15;
  const int tok0 = blockIdx.x * 16;
  const int b = tok0 >> 12, nl = tok0 & 4095;

  if (tid < 64) {
    int tokr = tid >> 2, hh = tid & 3;
    int bh = b * 4 + hh;
    int n = nl + tokr;
    float s = 0.f;
#pragma unroll
    for (int q = 0; q < 4; ++q)
      s += Lp[((size_t)q * 8 + bh) * NN + n];
    linv[tokr * 4 + hh] = (s > 0.f) ? (1.f / s) : 0.f;
  }
  __syncthreads();

  {
    int tokr = tid >> 4, ch0 = (tid & 15) * 16;
    size_t base = ((size_t)b * NN + nl + tokr) * CDIM + ch0;
    float inv = linv[tokr * 4 + (ch0 >> 6)];
    float acc16[16];
#pragma unroll
    for (int i = 0; i < 16; ++i) acc16[i] = 0.f;
#pragma unroll
    for (int q = 0; q < 4; ++q) {
      size_t qb = (size_t)q * 2097152 + base;
      uint4 a0 = *reinterpret_cast<const uint4*>(Opb + qb);
      uint4 a1 = *reinterpret_cast<const uint4*>(Opb + qb + 8);
      unsigned wa[8] = {a0.x, a0.y, a0.z, a0.w, a1.x, a1.y, a1.z, a1.w};
#pragma unroll
      for (int i = 0; i < 8; ++i) {
        acc16[2 * i]     += bf2f((u16)(wa[i] & 0xffffu));
        acc16[2 * i + 1] += bf2f((u16)(wa[i] >> 16));
      }
    }
    u16 ov[16];
#pragma unroll
    for (int i = 0; i < 16; ++i) ov[i] = f2bf(acc16[i] * inv);
    u16* dst = &As[tokr * 264 + ch0];
    *reinterpret_cast<uint4*>(dst) = *reinterpret_cast<uint4*>(ov);
    *reinterpret_cast<uint4*>(dst + 8) = *reinterpret_cast<uint4*>(ov + 8);
  }
  __syncthreads();

  f32x4 acc[4];
#pragma unroll
  for (int i = 0; i < 4; ++i) acc[i] = (f32x4){0.f, 0.f, 0.f, 0.f};
#pragma unroll
  for (int ks = 0; ks < 8; ++ks) {
    short8 af = *reinterpret_cast<const short8*>(&As[l15 * 264 + ks * 32 + quad * 8]);
#pragma unroll
    for (int ns = 0; ns < 4; ++ns) {
      short8 bf = *reinterpret_cast<const short8*>(
          &Wob[(size_t)(w * 64 + ns * 16 + l15) * 256 + ks * 32 + quad * 8]);
      acc[ns] = __builtin_amdgcn_mfma_f32_16x16x32_bf16(af, bf, acc[ns], 0, 0, 0);
    }
  }

#pragma unroll
  for (int ns = 0; ns < 4; ++ns) {
    int ch = w * 64 + ns * 16 + l15;
    float bb = bo[ch];
#pragma unroll
    for (int r = 0; r < 4; ++r) ys[quad * 4 + r][ch] = acc[ns][r] + bb;
  }
  __syncthreads();

  float g[4], bt[4];
#pragma unroll
  for (int i = 0; i < 4; ++i) {
    g[i] = gamma[lane + i * 64];
    bt[i] = beta[lane + i * 64];
  }
#pragma unroll
  for (int rr = 0; rr < 4; ++rr) {
    int r = w * 4 + rr;
    float v[4], s = 0.f, s2 = 0.f;
#pragma unroll
    for (int i = 0; i < 4; ++i) {
      v[i] = ys[r][lane + i * 64];
      s += v[i];
      s2 = fmaf(v[i], v[i], s2);
    }
#pragma unroll
    for (int off = 32; off > 0; off >>= 1) {
      s += __shfl_xor(s, off, 64);
      s2 += __shfl_xor(s2, off, 64);
    }
    float mu = s * (1.f / 256.f);
    float rs = rsqrtf(s2 * (1.f / 256.f) - mu * mu + 1e-5f);
    float* orow = out + (size_t)(tok0 + r) * 256;
#pragma unroll
    for (int i = 0; i < 4; ++i)
      orow[lane + i * 64] = (v[i] - mu) * rs * g[i] + bt[i];
  }
}

// ---------------------------------------------------------------------------
extern "C" void kernel_launch(void* const* d_in, const int* in_sizes, int n_in,
                              void* d_out, int out_size, void* d_ws, size_t ws_size,
                              hipStream_t stream) {
  const float* x     = (const float*)d_in[0];
  const int*   adj   = (const int*)d_in[1];
  const float* Wq    = (const float*)d_in[2];
  const float* bq    = (const float*)d_in[3];
  const float* Wk    = (const float*)d_in[4];
  const float* bk    = (const float*)d_in[5];
  const float* Wv    = (const float*)d_in[6];
  const float* bv    = (const float*)d_in[7];
  const float* Wo    = (const float*)d_in[8];
  const float* bo    = (const float*)d_in[9];
  const float* gamma = (const float*)d_in[10];
  const float* beta  = (const float*)d_in[11];
  float* out = (float*)d_out;

  const size_t PER = (size_t)NB * HEADS * NN * HD;  // 2,097,152
  u16* Wqb = (u16*)d_ws;                 // 65,536 each
  u16* Wkb = Wqb + 65536;
  u16* Wvb = Wkb + 65536;
  u16* Wob = Wvb + 65536;
  u64* bmp = (u64*)(Wob + 65536);        // 524,288 u64 (4 MB), 8B-aligned
  u16* Qb  = (u16*)(bmp + 524288);
  u16* Kb  = Qb + PER;
  u16* Vtb = Kb + PER;
  u16* Opb = Vtb + PER;                  // 4 x PER bf16 (quarter partials)
  float* Lp = (float*)(Opb + 4 * PER);   // 131,072 fp32

  const size_t NEED = (size_t)((u16*)(Lp + 131072) - (u16*)d_ws) * sizeof(u16);
  if (ws_size < NEED) return;

  prep<<<dim3(4224), dim3(256), 0, stream>>>(
      adj, (u8*)bmp, Wq, Wk, Wv, Wo, Wqb, Wkb, Wvb, Wob);

  qkv_gemm<<<dim3(512, 3), dim3(256), 0, stream>>>(
      x, Wqb, Wkb, Wvb, bq, bk, bv, Qb, Kb, Vtb);

  // r21: 1-D XCD-aware grid (bh = fid&7 pins each head to one XCD's L2)
  attn_mfma<<<dim3(512), dim3(256), 0, stream>>>(
      Qb, Kb, Vtb, bmp, Opb, Lp);

  comb_oproj<<<dim3((NB * NN) / 16), dim3(256), 0, stream>>>(
      Opb, Lp, Wob, bo, gamma, beta, out);
}